// Round 3
// baseline (293.445 us; speedup 1.0000x reference)
//
#include <hip/hip_runtime.h>

typedef unsigned short u16;
typedef unsigned int u32;
typedef __attribute__((ext_vector_type(8))) short bf16x8;
typedef __attribute__((ext_vector_type(4))) float f32x4;

#define MFMA16 __builtin_amdgcn_mfma_f32_16x16x32_bf16

__device__ __forceinline__ u16 f2bf(float f) {
  u32 u = __builtin_bit_cast(u32, f);
  u = u + 0x7FFFu + ((u >> 16) & 1u);
  return (u16)(u >> 16);
}
__device__ __forceinline__ u32 pk2(float lo, float hi) {
  return (u32)f2bf(lo) | ((u32)f2bf(hi) << 16);
}
__device__ __forceinline__ float bf2f(u32 x) {
  return __builtin_bit_cast(float, x << 16);
}
__device__ __forceinline__ void gld16(const void* gp, void* lp) {
  __builtin_amdgcn_global_load_lds((const __attribute__((address_space(1))) u32*)gp,
                                   (__attribute__((address_space(3))) u32*)lp, 16, 0, 0);
}

// ---------------- kernel 0: fp32 -> bf16 convert (x, Wq|Wk|Wv) ----------------
__global__ __launch_bounds__(256) void cvt_kernel(
    const float* __restrict__ x, const float* __restrict__ wq,
    const float* __restrict__ wk, const float* __restrict__ wv,
    u16* __restrict__ xbf, u16* __restrict__ wbf) {
  int idx = blockIdx.x * 256 + threadIdx.x;
  if (idx < 1048576) {
    float4 v = ((const float4*)x)[idx];
    uint2 u; u.x = pk2(v.x, v.y); u.y = pk2(v.z, v.w);
    ((uint2*)xbf)[idx] = u;
  } else {
    int j = idx - 1048576;
    const float* W = (j < 16384) ? wq : (j < 32768) ? wk : wv;
    int k = j & 16383;
    float4 v = ((const float4*)W)[k];
    uint2 u; u.x = pk2(v.x, v.y); u.y = pk2(v.z, v.w);
    ((uint2*)wbf)[j] = u;
  }
}

// ---------------- kernel 1: QKV projection ----------------
// mat 0: Qs[s][e] = (x @ Wq^T) * (log2(e)/16)
// mat 1: Ks[s][e] =  x @ Wk^T
// mat 2: Vt[e][s] =  (x @ Wv^T)^T
__global__ __launch_bounds__(256, 2) void proj_kernel(
    const u16* __restrict__ xbf, const u16* __restrict__ wbf,
    u16* __restrict__ Qs, u16* __restrict__ Ks, u16* __restrict__ Vt) {
  int tile = blockIdx.x, mat = blockIdx.y;
  int tid = threadIdx.x, w = tid >> 6, lane = tid & 63, b15 = lane & 15, g = lane >> 4;
  int base = tile * 64 + w * 16;
  const u16* W = wbf + mat * 65536;
  const u16* Xp = xbf + (size_t)(base + b15) * 256;
  f32x4 acc[16] = {};
  if (mat < 2) {
#pragma unroll
    for (int kk = 0; kk < 8; ++kk) {
      bf16x8 xf = *(const bf16x8*)(Xp + kk * 32 + g * 8);
#pragma unroll
      for (int eb = 0; eb < 16; ++eb) {
        bf16x8 wf = *(const bf16x8*)(W + (size_t)(eb * 16 + b15) * 256 + kk * 32 + g * 8);
        acc[eb] = MFMA16(xf, wf, acc[eb], 0, 0, 0);
      }
    }
    float scale = (mat == 0) ? 0.0901684400555602f : 1.0f;  // log2(e)/16
    u16* dst = (mat == 0) ? Qs : Ks;
#pragma unroll
    for (int eb = 0; eb < 16; ++eb)
#pragma unroll
      for (int r = 0; r < 4; ++r)
        dst[(size_t)(base + g * 4 + r) * 256 + eb * 16 + b15] = f2bf(acc[eb][r] * scale);
  } else {
#pragma unroll
    for (int kk = 0; kk < 8; ++kk) {
      bf16x8 xf = *(const bf16x8*)(Xp + kk * 32 + g * 8);
#pragma unroll
      for (int eb = 0; eb < 16; ++eb) {
        bf16x8 wf = *(const bf16x8*)(W + (size_t)(eb * 16 + b15) * 256 + kk * 32 + g * 8);
        acc[eb] = MFMA16(wf, xf, acc[eb], 0, 0, 0);
      }
    }
    int sglob = base + b15;
    int b = sglob >> 12, sl = sglob & 4095;
#pragma unroll
    for (int eb = 0; eb < 16; ++eb)
#pragma unroll
      for (int r = 0; r < 4; ++r) {
        int e = eb * 16 + g * 4 + r;
        Vt[((size_t)(b * 256 + e) << 12) + sl] = f2bf(acc[eb][r]);
      }
  }
}

// ---------------- kernel 2: causal flash attention, kv-split partials ----------------
// Unit = (batch, 128-row q-tile, balanced kv-chunk). 576 blocks, heavy units first.
// K/V staged via global_load_lds, double-buffered, XOR-swizzled. Defer-max softmax
// (THR=8), per-lane partial l, split PV so acc0-PV overlaps softmax-half1.
__global__ __launch_bounds__(256, 2) void attn_kernel(
    const u16* __restrict__ Qs, const u16* __restrict__ Ks_,
    const u16* __restrict__ Vt_, u16* __restrict__ pacc, float2* __restrict__ pml) {
  __shared__ u16 Kd[2][8192];   // [buf][32 kv rows][256 d], 512B rows, swz byte^=(row&7)<<4
  __shared__ u16 Vd[2][8192];   // [buf][256 e rows][32 kv], 64B rows, quad-swz

  int bid = blockIdx.x;
  int xcd = bid & 7;
  int b = xcd >> 1;                          // batch -> XCD pair (L2 affinity)
  int u = 143 - ((bid >> 3) * 2 + (xcd & 1)); // reversed: heavy units dispatch first
  int g4 = 0;
#pragma unroll
  for (int t = 1; t <= 7; ++t) g4 += (u >= 2 * t * (t + 1)) ? 1 : 0;
  int v = u - 2 * g4 * (g4 + 1);
  int tt = 4 * g4 + v / (g4 + 1);            // q-tile 0..31
  int c = v % (g4 + 1);                      // chunk within tile
  int uid = b * 144 + u;

  int tid = threadIdx.x, w = tid >> 6, lane = tid & 63, b15 = lane & 15, g = lane >> 4;
  int qbase = tt * 128 + w * 32;
  int nst = 4 * (tt + 1), nch = g4 + 1;      // balanced chunk bounds
  int kt0 = (c * nst) / nch, kt_end = ((c + 1) * nst) / nch;

  // loop-invariant staging offsets (inverse swizzle: LDS linear, source permuted)
  int Koff[4], Voff[4];
#pragma unroll
  for (int i = 0; i < 4; ++i) {
    int o = (w * 4 + i) * 1024 + lane * 16;
    int row = o >> 9;
    Koff[i] = row * 512 + ((o & 511) ^ ((row & 7) << 4));
    int e17 = o >> 7;
    int e = (e17 << 1) | (((o >> 6) & 1) ^ ((e17 >> 2) & 1));
    int gg = ((o >> 4) & 3) ^ (e17 & 3);
    Voff[i] = e * 8192 + gg * 16;
  }
  const char* Kgb = (const char*)(Ks_ + (size_t)b * 4096 * 256);
  const char* Vgb = (const char*)(Vt_ + (size_t)b * 1048576);
  char* KL = (char*)&Kd[0][0];
  char* VL = (char*)&Vd[0][0];

  auto stage = [&](int buf, int kt) {
    size_t kb = (size_t)kt * 32 * 512;
    size_t vb = (size_t)kt * 64;
#pragma unroll
    for (int i = 0; i < 4; ++i)
      gld16(Kgb + kb + Koff[i], KL + buf * 16384 + (w * 4 + i) * 1024);
#pragma unroll
    for (int i = 0; i < 4; ++i)
      gld16(Vgb + vb + Voff[i], VL + buf * 16384 + (w * 4 + i) * 1024);
  };

  // Q fragments for both 16-row halves (B-operand: col=q, k=d)
  const u16* Qp0 = Qs + ((size_t)b * 4096 + qbase + b15) * 256;
  bf16x8 qf0[8], qf1[8];
#pragma unroll
  for (int kk = 0; kk < 8; ++kk) {
    qf0[kk] = *(const bf16x8*)(Qp0 + kk * 32 + g * 8);
    qf1[kk] = *(const bf16x8*)(Qp0 + 16 * 256 + kk * 32 + g * 8);
  }

  f32x4 acc0[16] = {}, acc1[16] = {};
  float m0 = -3e38f, l0 = 0.f, m1 = -3e38f, l1 = 0.f;  // l per-lane partial
  stage(0, kt0);
  int cur = 0;

  for (int kt = kt0; kt < kt_end; ++kt) {
    __syncthreads();                              // buf[cur] landed
    if (kt + 1 < kt_end) stage(cur ^ 1, kt + 1);  // in flight under compute
    int kv0 = kt * 32;
    if (kv0 <= qbase + 31) {
      const char* Kc = KL + cur * 16384;
      const char* Vc = VL + cur * 16384;
      f32x4 s00 = {0,0,0,0}, s10 = {0,0,0,0}, s01 = {0,0,0,0}, s11 = {0,0,0,0};
      __builtin_amdgcn_s_setprio(1);
#pragma unroll
      for (int kk = 0; kk < 8; ++kk) {
        int cb = (kk * 64 + g * 16) ^ ((b15 & 7) << 4);
        bf16x8 k0 = *(const bf16x8*)(Kc + b15 * 512 + cb);
        bf16x8 k1 = *(const bf16x8*)(Kc + (16 + b15) * 512 + cb);
        s00 = MFMA16(k0, qf0[kk], s00, 0, 0, 0);
        s10 = MFMA16(k1, qf0[kk], s10, 0, 0, 0);
        s01 = MFMA16(k0, qf1[kk], s01, 0, 0, 0);
        s11 = MFMA16(k1, qf1[kk], s11, 0, 0, 0);
      }
      __builtin_amdgcn_s_setprio(0);
      if (kv0 + 31 > qbase) {  // diagonal: mask kv > qrow
        int q0 = qbase + b15, q1 = q0 + 16;
#pragma unroll
        for (int r = 0; r < 4; ++r) {
          int ka = kv0 + g * 4 + r, kb2 = ka + 16;
          if (ka > q0) s00[r] = -3e38f;
          if (kb2 > q0) s10[r] = -3e38f;
          if (ka > q1) s01[r] = -3e38f;
          if (kb2 > q1) s11[r] = -3e38f;
        }
      }
      bf16x8 pb0, pb1;
      {  // softmax half 0 (defer-max)
        float pm = fmaxf(fmaxf(fmaxf(s00[0], s00[1]), fmaxf(s00[2], s00[3])),
                         fmaxf(fmaxf(s10[0], s10[1]), fmaxf(s10[2], s10[3])));
        pm = fmaxf(pm, __shfl_xor(pm, 16));
        pm = fmaxf(pm, __shfl_xor(pm, 32));
        if (__any(pm > m0 + 8.f)) {
          float mn = fmaxf(m0, pm);
          float sc = exp2f(m0 - mn);
          l0 *= sc;
#pragma unroll
          for (int eb = 0; eb < 16; ++eb) acc0[eb] *= sc;
          m0 = mn;
        }
        float p0[4], p1[4];
#pragma unroll
        for (int r = 0; r < 4; ++r) {
          p0[r] = exp2f(s00[r] - m0); p1[r] = exp2f(s10[r] - m0);
          l0 += p0[r] + p1[r];
        }
        u32 f0d0 = pk2(p0[0], p0[1]), f0d1 = pk2(p0[2], p0[3]);
        u32 f1d0 = pk2(p1[0], p1[1]), f1d1 = pk2(p1[2], p1[3]);
        int srcA = b15 + 32 * (g & 1), srcB = srcA + 16;
        u32 a0 = (u32)__shfl((int)f0d0, srcA), a1 = (u32)__shfl((int)f0d1, srcA);
        u32 a2 = (u32)__shfl((int)f0d0, srcB), a3 = (u32)__shfl((int)f0d1, srcB);
        u32 c0 = (u32)__shfl((int)f1d0, srcA), c1 = (u32)__shfl((int)f1d1, srcA);
        u32 c2 = (u32)__shfl((int)f1d0, srcB), c3 = (u32)__shfl((int)f1d1, srcB);
        bool hi = (g >= 2);
        union { u32 uu[4]; bf16x8 vv; } pu;
        pu.uu[0] = hi ? c0 : a0; pu.uu[1] = hi ? c1 : a1;
        pu.uu[2] = hi ? c2 : a2; pu.uu[3] = hi ? c3 : a3;
        pb0 = pu.vv;
      }
      // PV half 0 — depends only on pb0; overlaps softmax half 1 below
      __builtin_amdgcn_s_setprio(1);
#pragma unroll
      for (int eb = 0; eb < 16; ++eb) {
        int e = eb * 16 + b15;
        bf16x8 vf = *(const bf16x8*)(Vc + ((e << 6) ^ (((((e >> 1) & 7)) ^ g) << 4)));
        acc0[eb] = MFMA16(vf, pb0, acc0[eb], 0, 0, 0);
      }
      __builtin_amdgcn_s_setprio(0);
      {  // softmax half 1 (defer-max)
        float pm = fmaxf(fmaxf(fmaxf(s01[0], s01[1]), fmaxf(s01[2], s01[3])),
                         fmaxf(fmaxf(s11[0], s11[1]), fmaxf(s11[2], s11[3])));
        pm = fmaxf(pm, __shfl_xor(pm, 16));
        pm = fmaxf(pm, __shfl_xor(pm, 32));
        if (__any(pm > m1 + 8.f)) {
          float mn = fmaxf(m1, pm);
          float sc = exp2f(m1 - mn);
          l1 *= sc;
#pragma unroll
          for (int eb = 0; eb < 16; ++eb) acc1[eb] *= sc;
          m1 = mn;
        }
        float p0[4], p1[4];
#pragma unroll
        for (int r = 0; r < 4; ++r) {
          p0[r] = exp2f(s01[r] - m1); p1[r] = exp2f(s11[r] - m1);
          l1 += p0[r] + p1[r];
        }
        u32 f0d0 = pk2(p0[0], p0[1]), f0d1 = pk2(p0[2], p0[3]);
        u32 f1d0 = pk2(p1[0], p1[1]), f1d1 = pk2(p1[2], p1[3]);
        int srcA = b15 + 32 * (g & 1), srcB = srcA + 16;
        u32 a0 = (u32)__shfl((int)f0d0, srcA), a1 = (u32)__shfl((int)f0d1, srcA);
        u32 a2 = (u32)__shfl((int)f0d0, srcB), a3 = (u32)__shfl((int)f0d1, srcB);
        u32 c0 = (u32)__shfl((int)f1d0, srcA), c1 = (u32)__shfl((int)f1d1, srcA);
        u32 c2 = (u32)__shfl((int)f1d0, srcB), c3 = (u32)__shfl((int)f1d1, srcB);
        bool hi = (g >= 2);
        union { u32 uu[4]; bf16x8 vv; } pu;
        pu.uu[0] = hi ? c0 : a0; pu.uu[1] = hi ? c1 : a1;
        pu.uu[2] = hi ? c2 : a2; pu.uu[3] = hi ? c3 : a3;
        pb1 = pu.vv;
      }
      // PV half 1
      __builtin_amdgcn_s_setprio(1);
#pragma unroll
      for (int eb = 0; eb < 16; ++eb) {
        int e = eb * 16 + b15;
        bf16x8 vf = *(const bf16x8*)(Vc + ((e << 6) ^ (((((e >> 1) & 7)) ^ g) << 4)));
        acc1[eb] = MFMA16(vf, pb1, acc1[eb], 0, 0, 0);
      }
      __builtin_amdgcn_s_setprio(0);
    }
    cur ^= 1;
  }

  // reduce per-lane partial l across the 4 row-copies
  l0 += __shfl_xor(l0, 16); l0 += __shfl_xor(l0, 32);
  l1 += __shfl_xor(l1, 16); l1 += __shfl_xor(l1, 32);

  // store partials (unnormalized acc in bf16, m/l in fp32)
  u16* pp0 = pacc + ((size_t)uid * 128 + w * 32 + b15) * 256;
  u16* pp1 = pp0 + 16 * 256;
#pragma unroll
  for (int eb = 0; eb < 16; ++eb) {
    uint2 u0, u1;
    u0.x = pk2(acc0[eb][0], acc0[eb][1]); u0.y = pk2(acc0[eb][2], acc0[eb][3]);
    u1.x = pk2(acc1[eb][0], acc1[eb][1]); u1.y = pk2(acc1[eb][2], acc1[eb][3]);
    *(uint2*)(pp0 + eb * 16 + g * 4) = u0;
    *(uint2*)(pp1 + eb * 16 + g * 4) = u1;
  }
  if (g == 0) {
    float2 a; a.x = m0; a.y = l0;
    float2 bb; bb.x = m1; bb.y = l1;
    pml[(size_t)uid * 128 + w * 32 + b15] = a;
    pml[(size_t)uid * 128 + w * 32 + 16 + b15] = bb;
  }
}

// ---------------- kernel 3: combine partials ----------------
__global__ __launch_bounds__(256) void combine_kernel(
    const u16* __restrict__ pacc, const float2* __restrict__ pml,
    float* __restrict__ out) {
  int row = blockIdx.x * 4 + (threadIdx.x >> 6);
  int lane = threadIdx.x & 63;
  int b = row >> 12, r = row & 4095;
  int tt = r >> 7, rin = r & 127;
  int g4 = tt >> 2, nch = g4 + 1;
  int ubase = b * 144 + 2 * g4 * (g4 + 1) + (tt & 3) * (g4 + 1);
  float M = -3e38f;
  for (int cc = 0; cc < nch; ++cc)
    M = fmaxf(M, pml[(size_t)(ubase + cc) * 128 + rin].x);
  float L = 0.f, o0 = 0.f, o1 = 0.f, o2 = 0.f, o3 = 0.f;
  for (int cc = 0; cc < nch; ++cc) {
    float2 ml = pml[(size_t)(ubase + cc) * 128 + rin];
    float s = exp2f(ml.x - M);
    L += ml.y * s;
    uint2 a = *(const uint2*)(pacc + ((size_t)(ubase + cc) * 128 + rin) * 256 + lane * 4);
    o0 += s * bf2f(a.x & 0xffffu); o1 += s * bf2f(a.x >> 16);
    o2 += s * bf2f(a.y & 0xffffu); o3 += s * bf2f(a.y >> 16);
  }
  float inv = 1.f / L;
  f32x4 res = {o0 * inv, o1 * inv, o2 * inv, o3 * inv};
  *(f32x4*)(out + (size_t)row * 256 + lane * 4) = res;
}

// ---------------- launch ----------------
extern "C" void kernel_launch(void* const* d_in, const int* in_sizes, int n_in,
                              void* d_out, int out_size, void* d_ws, size_t ws_size,
                              hipStream_t stream) {
  const float* x = (const float*)d_in[0];
  const float* wq = (const float*)d_in[1];
  const float* wk = (const float*)d_in[2];
  const float* wv = (const float*)d_in[3];
  char* ws = (char*)d_ws;
  u16* xbf = (u16*)(ws);                    // 8 MB
  u16* wbf = (u16*)(ws + 8388608);          // 384 KB
  u16* Qs  = (u16*)(ws + 9437184);          // 8 MB (pre-scaled)
  u16* Ks  = (u16*)(ws + 17825792);         // 8 MB
  u16* Vt  = (u16*)(ws + 26214400);         // 8 MB [b][e][s]
  u16* pacc = (u16*)(ws + 34603008);        // 36 MB partial acc (bf16)
  float2* pml = (float2*)(ws + 72351744);   // 576 KB partial m/l
  float* out = (float*)d_out;

  hipLaunchKernelGGL(cvt_kernel, dim3(4288), dim3(256), 0, stream, x, wq, wk, wv, xbf, wbf);
  hipLaunchKernelGGL(proj_kernel, dim3(256, 3), dim3(256), 0, stream, xbf, wbf, Qs, Ks, Vt);
  hipLaunchKernelGGL(attn_kernel, dim3(576), dim3(256), 0, stream, Qs, Ks, Vt, pacc, pml);
  hipLaunchKernelGGL(combine_kernel, dim3(4096), dim3(256), 0, stream, pacc, pml, out);
}

// Round 5
// 178.593 us; speedup vs baseline: 1.6431x; 1.6431x over previous
//
#include <hip/hip_runtime.h>

typedef unsigned short u16;
typedef unsigned int u32;
typedef __attribute__((ext_vector_type(8))) short bf16x8;
typedef __attribute__((ext_vector_type(4))) float f32x4;
typedef __attribute__((ext_vector_type(16))) float f32x16;

#define MFMA16 __builtin_amdgcn_mfma_f32_16x16x32_bf16
#define MFMA32 __builtin_amdgcn_mfma_f32_32x32x16_bf16

__device__ __forceinline__ u16 f2bf(float f) {
  u32 u = __builtin_bit_cast(u32, f);
  u = u + 0x7FFFu + ((u >> 16) & 1u);
  return (u16)(u >> 16);
}
__device__ __forceinline__ u32 pk2(float lo, float hi) {
  return (u32)f2bf(lo) | ((u32)f2bf(hi) << 16);
}
__device__ __forceinline__ float bf2f(u32 x) {
  return __builtin_bit_cast(float, x << 16);
}
__device__ __forceinline__ u32 cvtpk(float lo, float hi) {
  u32 r;
  asm("v_cvt_pk_bf16_f32 %0, %1, %2" : "=v"(r) : "v"(lo), "v"(hi));
  return r;
}
// v_permlane32_swap_b32 a, b : exchanges a.hi(lanes32-63) with b.lo(lanes0-31)
//   -> new a = {a.lo, b.lo}, new b = {a.hi, b.hi}
__device__ __forceinline__ void pswap(u32& x, u32& y) {
  asm("v_permlane32_swap_b32 %0, %1" : "+v"(x), "+v"(y));
}
__device__ __forceinline__ void gld16(const void* gp, void* lp) {
  __builtin_amdgcn_global_load_lds((const __attribute__((address_space(1))) u32*)gp,
                                   (__attribute__((address_space(3))) u32*)lp, 16, 0, 0);
}

// ---------------- kernel 0: fp32 -> bf16 convert (x, Wq|Wk|Wv) ----------------
__global__ __launch_bounds__(256) void cvt_kernel(
    const float* __restrict__ x, const float* __restrict__ wq,
    const float* __restrict__ wk, const float* __restrict__ wv,
    u16* __restrict__ xbf, u16* __restrict__ wbf) {
  int idx = blockIdx.x * 256 + threadIdx.x;
  if (idx < 1048576) {
    float4 v = ((const float4*)x)[idx];
    uint2 u; u.x = pk2(v.x, v.y); u.y = pk2(v.z, v.w);
    ((uint2*)xbf)[idx] = u;
  } else {
    int j = idx - 1048576;
    const float* W = (j < 16384) ? wq : (j < 32768) ? wk : wv;
    int k = j & 16383;
    float4 v = ((const float4*)W)[k];
    uint2 u; u.x = pk2(v.x, v.y); u.y = pk2(v.z, v.w);
    ((uint2*)wbf)[j] = u;
  }
}

// ---------------- kernel 1: QKV projection ----------------
// mat 0: Qs[s][e] = (x @ Wq^T) * (log2(e)/16)
// mat 1: Ks[s][e] =  x @ Wk^T
// mat 2: Vt[e][s] =  (x @ Wv^T)^T
__global__ __launch_bounds__(256, 2) void proj_kernel(
    const u16* __restrict__ xbf, const u16* __restrict__ wbf,
    u16* __restrict__ Qs, u16* __restrict__ Ks, u16* __restrict__ Vt) {
  int tile = blockIdx.x, mat = blockIdx.y;
  int tid = threadIdx.x, w = tid >> 6, lane = tid & 63, b15 = lane & 15, g = lane >> 4;
  int base = tile * 64 + w * 16;
  const u16* W = wbf + mat * 65536;
  const u16* Xp = xbf + (size_t)(base + b15) * 256;
  f32x4 acc[16] = {};
  if (mat < 2) {
#pragma unroll
    for (int kk = 0; kk < 8; ++kk) {
      bf16x8 xf = *(const bf16x8*)(Xp + kk * 32 + g * 8);
#pragma unroll
      for (int eb = 0; eb < 16; ++eb) {
        bf16x8 wf = *(const bf16x8*)(W + (size_t)(eb * 16 + b15) * 256 + kk * 32 + g * 8);
        acc[eb] = MFMA16(xf, wf, acc[eb], 0, 0, 0);
      }
    }
    float scale = (mat == 0) ? 0.0901684400555602f : 1.0f;  // log2(e)/16
    u16* dst = (mat == 0) ? Qs : Ks;
#pragma unroll
    for (int eb = 0; eb < 16; ++eb)
#pragma unroll
      for (int r = 0; r < 4; ++r)
        dst[(size_t)(base + g * 4 + r) * 256 + eb * 16 + b15] = f2bf(acc[eb][r] * scale);
  } else {
#pragma unroll
    for (int kk = 0; kk < 8; ++kk) {
      bf16x8 xf = *(const bf16x8*)(Xp + kk * 32 + g * 8);
#pragma unroll
      for (int eb = 0; eb < 16; ++eb) {
        bf16x8 wf = *(const bf16x8*)(W + (size_t)(eb * 16 + b15) * 256 + kk * 32 + g * 8);
        acc[eb] = MFMA16(wf, xf, acc[eb], 0, 0, 0);
      }
    }
    int sglob = base + b15;
    int b = sglob >> 12, sl = sglob & 4095;
#pragma unroll
    for (int eb = 0; eb < 16; ++eb)
#pragma unroll
      for (int r = 0; r < 4; ++r) {
        int e = eb * 16 + g * 4 + r;
        Vt[((size_t)(b * 256 + e) << 12) + sl] = f2bf(acc[eb][r]);
      }
  }
}

// ---------------- kernel 2: causal flash attention, 32x32 MFMA, kv-split ----------------
// Unit = (batch, 128-row q-tile, aligned 512-kv chunk) as in R2. 4 waves x 32 q-rows
// via mfma_f32_32x32x16. One softmax per step; P repack = 8 cvt_pk + 4 permlane32_swap
// (zero LDS-permutes). K swz ^((row&15)<<4); V [256e][32kv] ^((e&3)<<4).
__global__ __launch_bounds__(256, 2) void attn_kernel(
    const u16* __restrict__ Qs, const u16* __restrict__ Ks_,
    const u16* __restrict__ Vt_, u16* __restrict__ pacc, float2* __restrict__ pml) {
  __shared__ u16 Kd[2][8192];   // [buf][32 kv][256 d] 512B rows
  __shared__ u16 Vd[2][8192];   // [buf][256 e][32 kv] 64B rows

  int bid = blockIdx.x;
  int xcd = bid & 7;
  int b = xcd >> 1;                       // batch -> XCD pair (L2 affinity)
  int u = (bid >> 3) * 2 + (xcd & 1);     // 0..143 (R2 order)
  int g4 = 0;
#pragma unroll
  for (int t = 1; t <= 7; ++t) g4 += (u >= 2 * t * (t + 1)) ? 1 : 0;
  int v = u - 2 * g4 * (g4 + 1);
  int tt = 4 * g4 + v / (g4 + 1);         // q-tile 0..31
  int c = v % (g4 + 1);                   // chunk within tile
  int uid = b * 144 + u;

  int tid = threadIdx.x, w = tid >> 6, lane = tid & 63;
  int l31 = lane & 31, h = lane >> 5;
  int qbase = tt * 128 + w * 32;
  int qrow = qbase + l31;
  int kt0 = c * 16, kt_end = min(kt0 + 16, 4 * (tt + 1));

  // staging source offsets (inverse swizzle; LDS linear, source permuted)
  int Koff[4], Voff[4];
#pragma unroll
  for (int i = 0; i < 4; ++i) {
    int o = (w * 4 + i) * 1024 + lane * 16;
    int row = o >> 9;
    Koff[i] = row * 512 + ((o & 511) ^ ((row & 15) << 4));
    int e = o >> 6;
    Voff[i] = e * 8192 + ((o & 63) ^ ((e & 3) << 4));
  }
  const char* Kgb = (const char*)(Ks_ + (size_t)b * 4096 * 256);
  const char* Vgb = (const char*)(Vt_ + (size_t)b * 1048576);
  char* KL = (char*)&Kd[0][0];
  char* VL = (char*)&Vd[0][0];

  auto stage = [&](int buf, int kt) {
    size_t kb = (size_t)kt * 32 * 512;
    size_t vb = (size_t)kt * 64;
#pragma unroll
    for (int i = 0; i < 4; ++i)
      gld16(Kgb + kb + Koff[i], KL + buf * 16384 + (w * 4 + i) * 1024);
#pragma unroll
    for (int i = 0; i < 4; ++i)
      gld16(Vgb + vb + Voff[i], VL + buf * 16384 + (w * 4 + i) * 1024);
  };

  // Q fragments (B-operand of 32x32x16: col=q=l31, k = kc*16 + h*8 + 0..7)
  const u16* Qrow = Qs + ((size_t)b * 4096 + qrow) * 256;
  bf16x8 qf[16];
#pragma unroll
  for (int kc = 0; kc < 16; ++kc)
    qf[kc] = *(const bf16x8*)(Qrow + kc * 16 + h * 8);

  f32x16 acc[8] = {};
  float m0 = -3e38f, l0 = 0.f;
  stage(0, kt0);
  int cur = 0;

  for (int kt = kt0; kt < kt_end; ++kt) {
    __syncthreads();                              // buf[cur] landed
    if (kt + 1 < kt_end) stage(cur ^ 1, kt + 1);  // fly during compute
    int kv0 = kt * 32;
    if (kv0 <= qbase + 31) {
      const char* Kc = KL + cur * 16384;
      const char* Vc = VL + cur * 16384;
      // --- QK^T: S^T[kv 0..31][q 0..31], two interleaved chains ---
      f32x16 sA = {}, sB = {};
      __builtin_amdgcn_s_setprio(1);
#pragma unroll
      for (int kc = 0; kc < 16; kc += 2) {
        bf16x8 k0 = *(const bf16x8*)(Kc + l31 * 512 + ((kc * 32 + h * 16) ^ ((l31 & 15) << 4)));
        bf16x8 k1 = *(const bf16x8*)(Kc + l31 * 512 + (((kc + 1) * 32 + h * 16) ^ ((l31 & 15) << 4)));
        sA = MFMA32(k0, qf[kc], sA, 0, 0, 0);
        sB = MFMA32(k1, qf[kc + 1], sB, 0, 0, 0);
      }
      __builtin_amdgcn_s_setprio(0);
      f32x16 s = sA + sB;
      if (kv0 + 31 > qbase) {  // diagonal step: mask kv > qrow
#pragma unroll
        for (int r = 0; r < 16; ++r) {
          int kv = kv0 + (r & 3) + 8 * (r >> 2) + 4 * h;
          if (kv > qrow) s[r] = -3e38f;
        }
      }
      // --- softmax (base-2, defer-max THR=8) ---
      float pm = s[0];
#pragma unroll
      for (int r = 1; r < 16; ++r) pm = fmaxf(pm, s[r]);
      pm = fmaxf(pm, __shfl_xor(pm, 32));
      if (__any(pm > m0 + 8.f)) {
        float mn = fmaxf(m0, pm);
        float sc = exp2f(m0 - mn);
        l0 *= sc;
#pragma unroll
        for (int et = 0; et < 8; ++et) acc[et] *= sc;
        m0 = mn;
      }
      float p[16];
#pragma unroll
      for (int r = 0; r < 16; ++r) {
        p[r] = exp2f(s[r] - m0);
        l0 += p[r];
      }
      // --- repack P -> PV B-operands (8 cvt_pk + 4 permlane32_swap) ---
      // lane(l31,h) holds p[r] = P[kv=(r&3)+8*(r>>2)+4h][q=l31]
      // B reg j (call A) needs kv pair (h*8+2j, h*8+2j+1):
      //   regA0={w0.lo,w2.lo} regA2={w0.hi,w2.hi} -> pswap(w0,w2); same for odd pairs
      u32 w0 = cvtpk(p[0], p[1]),  w1 = cvtpk(p[2], p[3]);
      u32 w2 = cvtpk(p[4], p[5]),  w3 = cvtpk(p[6], p[7]);
      u32 w4 = cvtpk(p[8], p[9]),  w5 = cvtpk(p[10], p[11]);
      u32 w6 = cvtpk(p[12], p[13]), w7 = cvtpk(p[14], p[15]);
      pswap(w0, w2); pswap(w1, w3);   // -> B(kv 0..15):  [w0,w1,w2,w3]
      pswap(w4, w6); pswap(w5, w7);   // -> B(kv 16..31): [w4,w5,w6,w7]
      union { u32 uu[4]; bf16x8 vv; } pA, pB;
      pA.uu[0] = w0; pA.uu[1] = w1; pA.uu[2] = w2; pA.uu[3] = w3;
      pB.uu[0] = w4; pB.uu[1] = w5; pB.uu[2] = w6; pB.uu[3] = w7;
      // --- PV: O^T[e][q] += V^T x P^T, 8 e-tiles x 2 kv-halves ---
      __builtin_amdgcn_s_setprio(1);
#pragma unroll
      for (int et = 0; et < 8; ++et) {
        const char* vrow = Vc + (et * 32 + l31) * 64;
        bf16x8 vf0 = *(const bf16x8*)(vrow + ((h * 16) ^ ((l31 & 3) << 4)));
        bf16x8 vf1 = *(const bf16x8*)(vrow + ((32 + h * 16) ^ ((l31 & 3) << 4)));
        acc[et] = MFMA32(vf0, pA.vv, acc[et], 0, 0, 0);
        acc[et] = MFMA32(vf1, pB.vv, acc[et], 0, 0, 0);
      }
      __builtin_amdgcn_s_setprio(0);
    }
    cur ^= 1;
  }

  // full l across the two kv-half lanes of each q-row
  l0 += __shfl_xor(l0, 32);

  // store partials (unnormalized acc bf16; m/l fp32)
  u16* ppr = pacc + ((size_t)uid * 128 + w * 32 + l31) * 256;
#pragma unroll
  for (int et = 0; et < 8; ++et)
#pragma unroll
    for (int j = 0; j < 4; ++j) {
      uint2 o;
      o.x = pk2(acc[et][4 * j], acc[et][4 * j + 1]);
      o.y = pk2(acc[et][4 * j + 2], acc[et][4 * j + 3]);
      *(uint2*)(ppr + et * 32 + 8 * j + 4 * h) = o;
    }
  if (h == 0) {
    float2 a; a.x = m0; a.y = l0;
    pml[(size_t)uid * 128 + w * 32 + l31] = a;
  }
}

// ---------------- kernel 3: combine partials ----------------
__global__ __launch_bounds__(256) void combine_kernel(
    const u16* __restrict__ pacc, const float2* __restrict__ pml,
    float* __restrict__ out) {
  int row = blockIdx.x * 4 + (threadIdx.x >> 6);
  int lane = threadIdx.x & 63;
  int b = row >> 12, r = row & 4095;
  int tt = r >> 7, rin = r & 127;
  int g4 = tt >> 2, nch = g4 + 1;
  int ubase = b * 144 + 2 * g4 * (g4 + 1) + (tt & 3) * (g4 + 1);
  float M = -3e38f;
  for (int cc = 0; cc < nch; ++cc)
    M = fmaxf(M, pml[(size_t)(ubase + cc) * 128 + rin].x);
  float L = 0.f, o0 = 0.f, o1 = 0.f, o2 = 0.f, o3 = 0.f;
  for (int cc = 0; cc < nch; ++cc) {
    float2 ml = pml[(size_t)(ubase + cc) * 128 + rin];
    float s = exp2f(ml.x - M);
    L += ml.y * s;
    uint2 a = *(const uint2*)(pacc + ((size_t)(ubase + cc) * 128 + rin) * 256 + lane * 4);
    o0 += s * bf2f(a.x & 0xffffu); o1 += s * bf2f(a.x >> 16);
    o2 += s * bf2f(a.y & 0xffffu); o3 += s * bf2f(a.y >> 16);
  }
  float inv = 1.f / L;
  f32x4 res = {o0 * inv, o1 * inv, o2 * inv, o3 * inv};
  *(f32x4*)(out + (size_t)row * 256 + lane * 4) = res;
}

// ---------------- launch ----------------
extern "C" void kernel_launch(void* const* d_in, const int* in_sizes, int n_in,
                              void* d_out, int out_size, void* d_ws, size_t ws_size,
                              hipStream_t stream) {
  const float* x = (const float*)d_in[0];
  const float* wq = (const float*)d_in[1];
  const float* wk = (const float*)d_in[2];
  const float* wv = (const float*)d_in[3];
  char* ws = (char*)d_ws;
  u16* xbf = (u16*)(ws);                    // 8 MB
  u16* wbf = (u16*)(ws + 8388608);          // 384 KB
  u16* Qs  = (u16*)(ws + 9437184);          // 8 MB (pre-scaled)
  u16* Ks  = (u16*)(ws + 17825792);         // 8 MB
  u16* Vt  = (u16*)(ws + 26214400);         // 8 MB [b][e][s]
  u16* pacc = (u16*)(ws + 34603008);        // 36 MB partial acc (bf16)
  float2* pml = (float2*)(ws + 72351744);   // 576 KB partial m/l
  float* out = (float*)d_out;

  hipLaunchKernelGGL(cvt_kernel, dim3(4288), dim3(256), 0, stream, x, wq, wk, wv, xbf, wbf);
  hipLaunchKernelGGL(proj_kernel, dim3(256, 3), dim3(256), 0, stream, xbf, wbf, Qs, Ks, Vt);
  hipLaunchKernelGGL(attn_kernel, dim3(576), dim3(256), 0, stream, Qs, Ks, Vt, pacc, pml);
  hipLaunchKernelGGL(combine_kernel, dim3(4096), dim3(256), 0, stream, pacc, pml, out);
}

// Round 7
// 157.138 us; speedup vs baseline: 1.8674x; 1.1365x over previous
//
#include <hip/hip_runtime.h>

typedef unsigned short u16;
typedef unsigned int u32;
typedef __attribute__((ext_vector_type(8))) short bf16x8;
typedef __attribute__((ext_vector_type(4))) float f32x4;
typedef __attribute__((ext_vector_type(16))) float f32x16;

#define MFMA16 __builtin_amdgcn_mfma_f32_16x16x32_bf16
#define MFMA32 __builtin_amdgcn_mfma_f32_32x32x16_bf16

__device__ __forceinline__ u16 f2bf(float f) {
  u32 u = __builtin_bit_cast(u32, f);
  u = u + 0x7FFFu + ((u >> 16) & 1u);
  return (u16)(u >> 16);
}
__device__ __forceinline__ u32 pk2(float lo, float hi) {
  return (u32)f2bf(lo) | ((u32)f2bf(hi) << 16);
}
__device__ __forceinline__ float bf2f(u32 x) {
  return __builtin_bit_cast(float, x << 16);
}
__device__ __forceinline__ u32 cvtpk(float lo, float hi) {
  u32 r;
  asm("v_cvt_pk_bf16_f32 %0, %1, %2" : "=v"(r) : "v"(lo), "v"(hi));
  return r;
}
// v_permlane32_swap_b32 a, b : new a = {a.lo, b.lo}, new b = {a.hi, b.hi}
// ONLY safe with genuinely distinct source values (R5-proven in repack).
// Do NOT use with two copies of one value (suspected R6 correctness bug).
__device__ __forceinline__ void pswap(u32& x, u32& y) {
  asm("v_permlane32_swap_b32 %0, %1" : "+v"(x), "+v"(y));
}
__device__ __forceinline__ void gld16(const void* gp, void* lp) {
  __builtin_amdgcn_global_load_lds((const __attribute__((address_space(1))) u32*)gp,
                                   (__attribute__((address_space(3))) u32*)lp, 16, 0, 0);
}

// ---------------- kernel 0: fp32 -> bf16 convert (x, Wq|Wk|Wv) ----------------
__global__ __launch_bounds__(256) void cvt_kernel(
    const float* __restrict__ x, const float* __restrict__ wq,
    const float* __restrict__ wk, const float* __restrict__ wv,
    u16* __restrict__ xbf, u16* __restrict__ wbf) {
  int idx = blockIdx.x * 256 + threadIdx.x;
  if (idx < 1048576) {
    float4 v = ((const float4*)x)[idx];
    uint2 u; u.x = pk2(v.x, v.y); u.y = pk2(v.z, v.w);
    ((uint2*)xbf)[idx] = u;
  } else {
    int j = idx - 1048576;
    const float* W = (j < 16384) ? wq : (j < 32768) ? wk : wv;
    int k = j & 16383;
    float4 v = ((const float4*)W)[k];
    uint2 u; u.x = pk2(v.x, v.y); u.y = pk2(v.z, v.w);
    ((uint2*)wbf)[j] = u;
  }
}

// ---------------- kernel 1: QKV projection ----------------
// mat 0: Qs[s][e] = (x @ Wq^T) * (log2(e)/16)
// mat 1: Ks[s][e] =  x @ Wk^T
// mat 2: Vt[e][s] =  (x @ Wv^T)^T
__global__ __launch_bounds__(256, 2) void proj_kernel(
    const u16* __restrict__ xbf, const u16* __restrict__ wbf,
    u16* __restrict__ Qs, u16* __restrict__ Ks, u16* __restrict__ Vt) {
  int tile = blockIdx.x, mat = blockIdx.y;
  int tid = threadIdx.x, w = tid >> 6, lane = tid & 63, b15 = lane & 15, g = lane >> 4;
  int base = tile * 64 + w * 16;
  const u16* W = wbf + mat * 65536;
  const u16* Xp = xbf + (size_t)(base + b15) * 256;
  f32x4 acc[16] = {};
  if (mat < 2) {
#pragma unroll
    for (int kk = 0; kk < 8; ++kk) {
      bf16x8 xf = *(const bf16x8*)(Xp + kk * 32 + g * 8);
#pragma unroll
      for (int eb = 0; eb < 16; ++eb) {
        bf16x8 wf = *(const bf16x8*)(W + (size_t)(eb * 16 + b15) * 256 + kk * 32 + g * 8);
        acc[eb] = MFMA16(xf, wf, acc[eb], 0, 0, 0);
      }
    }
    float scale = (mat == 0) ? 0.0901684400555602f : 1.0f;  // log2(e)/16
    u16* dst = (mat == 0) ? Qs : Ks;
#pragma unroll
    for (int eb = 0; eb < 16; ++eb)
#pragma unroll
      for (int r = 0; r < 4; ++r)
        dst[(size_t)(base + g * 4 + r) * 256 + eb * 16 + b15] = f2bf(acc[eb][r] * scale);
  } else {
#pragma unroll
    for (int kk = 0; kk < 8; ++kk) {
      bf16x8 xf = *(const bf16x8*)(Xp + kk * 32 + g * 8);
#pragma unroll
      for (int eb = 0; eb < 16; ++eb) {
        bf16x8 wf = *(const bf16x8*)(W + (size_t)(eb * 16 + b15) * 256 + kk * 32 + g * 8);
        acc[eb] = MFMA16(wf, xf, acc[eb], 0, 0, 0);
      }
    }
    int sglob = base + b15;
    int b = sglob >> 12, sl = sglob & 4095;
#pragma unroll
    for (int eb = 0; eb < 16; ++eb)
#pragma unroll
      for (int r = 0; r < 4; ++r) {
        int e = eb * 16 + g * 4 + r;
        Vt[((size_t)(b * 256 + e) << 12) + sl] = f2bf(acc[eb][r]);
      }
  }
}

// ---------------- kernel 2: causal flash attention, 32x32 MFMA, balanced LPT jobs ----
// 512 jobs (128/batch), every CU exactly 2 blocks. 112 full 16-step chunks are
// singleton jobs; 32 remainder chunks paired (4+16, 8+12) into 16 jobs of 20 steps,
// dispatched first (LPT). Aligned 16-step kv-chunks preserved (L2 sharing).
// V swizzle: col ^ ((e>>1&3)<<4) -> 2-way on PV reads (free). pm/l via shfl_xor.
__global__ __launch_bounds__(256, 2) void attn_kernel(
    const u16* __restrict__ Qs, const u16* __restrict__ Ks_,
    const u16* __restrict__ Vt_, u16* __restrict__ pacc, float2* __restrict__ pml) {
  __shared__ u16 Kd[2][8192];   // [buf][32 kv][256 d] 512B rows, swz ^((row&15)<<4)
  __shared__ u16 Vd[2][8192];   // [buf][256 e][32 kv] 64B rows,  swz ^((e>>1&3)<<4)

  int bid = blockIdx.x;
  int xcd = bid & 7;
  int b = xcd >> 1;                           // batch -> XCD pair (L2 affinity)
  int j = ((bid >> 3) << 1) | (bid & 1);      // job 0..127 within batch
  int t0, c0, t1 = -1, c1 = 0;
  if (j < 16) {                               // paired remainder jobs (20 steps)
    int g = j & 7;
    if (j < 8) { t0 = 4 * g;     t1 = 4 * g + 3; }
    else       { t0 = 4 * g + 1; t1 = 4 * g + 2; }
    c0 = g; c1 = g;
  } else {                                    // singleton full-16 jobs
    int jj = j - 16;                          // 0..111
    int g = 1;
#pragma unroll
    for (int gg = 2; gg <= 7; ++gg) if (jj >= 2 * gg * (gg - 1)) g = gg;
    int r = jj - 2 * g * (g - 1);
    t0 = 4 * g + r / g; c0 = r % g;
  }

  int tid = threadIdx.x, w = tid >> 6, lane = tid & 63;
  int l31 = lane & 31, h = lane >> 5;

  // staging source offsets (inverse swizzle; LDS linear, source permuted)
  int Koff[4], Voff[4];
#pragma unroll
  for (int i = 0; i < 4; ++i) {
    int o = (w * 4 + i) * 1024 + lane * 16;
    int row = o >> 9;
    Koff[i] = row * 512 + ((o & 511) ^ ((row & 15) << 4));
    int e = o >> 6;
    Voff[i] = e * 8192 + ((o & 63) ^ (((e >> 1) & 3) << 4));
  }
  const char* Kgb = (const char*)(Ks_ + (size_t)b * 4096 * 256);
  const char* Vgb = (const char*)(Vt_ + (size_t)b * 1048576);
  char* KL = (char*)&Kd[0][0];
  char* VL = (char*)&Vd[0][0];

  auto stage = [&](int buf, int kt) {
    size_t kb = (size_t)kt * 32 * 512;
    size_t vb = (size_t)kt * 64;
#pragma unroll
    for (int i = 0; i < 4; ++i)
      gld16(Kgb + kb + Koff[i], KL + buf * 16384 + (w * 4 + i) * 1024);
#pragma unroll
    for (int i = 0; i < 4; ++i)
      gld16(Vgb + vb + Voff[i], VL + buf * 16384 + (w * 4 + i) * 1024);
  };

  auto process = [&](int tt, int c) {
    int g4 = tt >> 2;
    int uid = b * 144 + 2 * g4 * (g4 + 1) + (tt & 3) * (g4 + 1) + c;
    int qbase = tt * 128 + w * 32;
    int qrow = qbase + l31;
    int kt0 = 16 * c, kt_end = min(16 * c + 16, 4 * (tt + 1));

    const u16* Qrow = Qs + ((size_t)b * 4096 + qrow) * 256;
    bf16x8 qf[16];
#pragma unroll
    for (int kc = 0; kc < 16; ++kc)
      qf[kc] = *(const bf16x8*)(Qrow + kc * 16 + h * 8);

    f32x16 acc[8] = {};
    float m0 = -3e38f, l0 = 0.f;
    stage(0, kt0);
    int cur = 0;

    for (int kt = kt0; kt < kt_end; ++kt) {
      __syncthreads();                              // buf[cur] landed
      if (kt + 1 < kt_end) stage(cur ^ 1, kt + 1);  // fly during compute
      int kv0 = kt * 32;
      if (kv0 <= qbase + 31) {
        const char* Kc = KL + cur * 16384;
        const char* Vc = VL + cur * 16384;
        // --- QK^T: S^T[kv][q], two interleaved chains ---
        f32x16 sA = {}, sB = {};
        __builtin_amdgcn_s_setprio(1);
#pragma unroll
        for (int kc = 0; kc < 16; kc += 2) {
          bf16x8 k0 = *(const bf16x8*)(Kc + l31 * 512 + ((kc * 32 + h * 16) ^ ((l31 & 15) << 4)));
          bf16x8 k1 = *(const bf16x8*)(Kc + l31 * 512 + (((kc + 1) * 32 + h * 16) ^ ((l31 & 15) << 4)));
          sA = MFMA32(k0, qf[kc], sA, 0, 0, 0);
          sB = MFMA32(k1, qf[kc + 1], sB, 0, 0, 0);
        }
        __builtin_amdgcn_s_setprio(0);
        f32x16 s = sA + sB;
        if (kv0 + 31 > qbase) {  // diagonal: mask kv > qrow
#pragma unroll
          for (int r = 0; r < 16; ++r) {
            int kv = kv0 + (r & 3) + 8 * (r >> 2) + 4 * h;
            if (kv > qrow) s[r] = -3e38f;
          }
        }
        // --- softmax (base-2, defer-max THR=8) ---
        float pm = s[0];
#pragma unroll
        for (int r = 1; r < 16; ++r) pm = fmaxf(pm, s[r]);
        pm = fmaxf(pm, __shfl_xor(pm, 32));
        if (__any(pm > m0 + 8.f)) {
          float mn = fmaxf(m0, pm);
          float sc = exp2f(m0 - mn);
          l0 *= sc;
#pragma unroll
          for (int et = 0; et < 8; ++et) acc[et] *= sc;
          m0 = mn;
        }
        float p[16];
#pragma unroll
        for (int r = 0; r < 16; ++r) {
          p[r] = exp2f(s[r] - m0);
          l0 += p[r];
        }
        // --- repack P -> PV B-operands (8 cvt_pk + 4 permlane32_swap) ---
        u32 w0 = cvtpk(p[0], p[1]),   w1 = cvtpk(p[2], p[3]);
        u32 w2 = cvtpk(p[4], p[5]),   w3 = cvtpk(p[6], p[7]);
        u32 w4 = cvtpk(p[8], p[9]),   w5 = cvtpk(p[10], p[11]);
        u32 w6 = cvtpk(p[12], p[13]), w7 = cvtpk(p[14], p[15]);
        pswap(w0, w2); pswap(w1, w3);   // -> B(kv 0..15):  [w0,w1,w2,w3]
        pswap(w4, w6); pswap(w5, w7);   // -> B(kv 16..31): [w4,w5,w6,w7]
        union { u32 uu[4]; bf16x8 vv; } pA, pB;
        pA.uu[0] = w0; pA.uu[1] = w1; pA.uu[2] = w2; pA.uu[3] = w3;
        pB.uu[0] = w4; pB.uu[1] = w5; pB.uu[2] = w6; pB.uu[3] = w7;
        // --- PV: O^T[e][q] += V^T x P^T ---
        __builtin_amdgcn_s_setprio(1);
#pragma unroll
        for (int et = 0; et < 8; ++et) {
          const char* vrow = Vc + (et * 32 + l31) * 64;
          int swz = ((l31 >> 1) & 3) << 4;
          bf16x8 vf0 = *(const bf16x8*)(vrow + ((h * 16) ^ swz));
          bf16x8 vf1 = *(const bf16x8*)(vrow + ((32 + h * 16) ^ swz));
          acc[et] = MFMA32(vf0, pA.vv, acc[et], 0, 0, 0);
          acc[et] = MFMA32(vf1, pB.vv, acc[et], 0, 0, 0);
        }
        __builtin_amdgcn_s_setprio(0);
      }
      cur ^= 1;
    }

    // l across the two kv-half lanes
    l0 += __shfl_xor(l0, 32);

    // store partials (unnormalized acc bf16; m/l fp32)
    u16* ppr = pacc + ((size_t)uid * 128 + w * 32 + l31) * 256;
#pragma unroll
    for (int et = 0; et < 8; ++et)
#pragma unroll
      for (int jj = 0; jj < 4; ++jj) {
        uint2 o;
        o.x = pk2(acc[et][4 * jj], acc[et][4 * jj + 1]);
        o.y = pk2(acc[et][4 * jj + 2], acc[et][4 * jj + 3]);
        *(uint2*)(ppr + et * 32 + 8 * jj + 4 * h) = o;
      }
    if (h == 0) {
      float2 a; a.x = m0; a.y = l0;
      pml[(size_t)uid * 128 + w * 32 + l31] = a;
    }
  };

  process(t0, c0);
  if (t1 >= 0) {
    __syncthreads();   // all waves done reading LDS before re-staging
    process(t1, c1);
  }
}

// ---------------- kernel 3: combine partials ----------------
__global__ __launch_bounds__(256) void combine_kernel(
    const u16* __restrict__ pacc, const float2* __restrict__ pml,
    float* __restrict__ out) {
  int row = blockIdx.x * 4 + (threadIdx.x >> 6);
  int lane = threadIdx.x & 63;
  int b = row >> 12, r = row & 4095;
  int tt = r >> 7, rin = r & 127;
  int g4 = tt >> 2, nch = g4 + 1;
  int ubase = b * 144 + 2 * g4 * (g4 + 1) + (tt & 3) * (g4 + 1);
  float M = -3e38f;
  for (int cc = 0; cc < nch; ++cc)
    M = fmaxf(M, pml[(size_t)(ubase + cc) * 128 + rin].x);
  float L = 0.f, o0 = 0.f, o1 = 0.f, o2 = 0.f, o3 = 0.f;
  for (int cc = 0; cc < nch; ++cc) {
    float2 ml = pml[(size_t)(ubase + cc) * 128 + rin];
    float s = exp2f(ml.x - M);
    L += ml.y * s;
    uint2 a = *(const uint2*)(pacc + ((size_t)(ubase + cc) * 128 + rin) * 256 + lane * 4);
    o0 += s * bf2f(a.x & 0xffffu); o1 += s * bf2f(a.x >> 16);
    o2 += s * bf2f(a.y & 0xffffu); o3 += s * bf2f(a.y >> 16);
  }
  float inv = 1.f / L;
  f32x4 res = {o0 * inv, o1 * inv, o2 * inv, o3 * inv};
  *(f32x4*)(out + (size_t)row * 256 + lane * 4) = res;
}

// ---------------- launch ----------------
extern "C" void kernel_launch(void* const* d_in, const int* in_sizes, int n_in,
                              void* d_out, int out_size, void* d_ws, size_t ws_size,
                              hipStream_t stream) {
  const float* x = (const float*)d_in[0];
  const float* wq = (const float*)d_in[1];
  const float* wk = (const float*)d_in[2];
  const float* wv = (const float*)d_in[3];
  char* ws = (char*)d_ws;
  u16* xbf = (u16*)(ws);                    // 8 MB
  u16* wbf = (u16*)(ws + 8388608);          // 384 KB
  u16* Qs  = (u16*)(ws + 9437184);          // 8 MB (pre-scaled)
  u16* Ks  = (u16*)(ws + 17825792);         // 8 MB
  u16* Vt  = (u16*)(ws + 26214400);         // 8 MB [b][e][s]
  u16* pacc = (u16*)(ws + 34603008);        // 36 MB partial acc (bf16)
  float2* pml = (float2*)(ws + 72351744);   // 576 KB partial m/l
  float* out = (float*)d_out;

  hipLaunchKernelGGL(cvt_kernel, dim3(4288), dim3(256), 0, stream, x, wq, wk, wv, xbf, wbf);
  hipLaunchKernelGGL(proj_kernel, dim3(256, 3), dim3(256), 0, stream, xbf, wbf, Qs, Ks, Vt);
  hipLaunchKernelGGL(attn_kernel, dim3(512), dim3(256), 0, stream, Qs, Ks, Vt, pacc, pml);
  hipLaunchKernelGGL(combine_kernel, dim3(4096), dim3(256), 0, stream, pacc, pml, out);
}